// Round 19
// baseline (353.429 us; speedup 1.0000x reference)
//
#include <hip/hip_runtime.h>

#define BB 2
#define LL 2048
#define DM 1024
#define DI 2048
#define NTOK (BB*LL)   // 4096
#define NC 64
#define CL (LL/NC)     // 32
#define NCH (BB*DI)    // 4096 channels total

typedef __bf16 bf16x8 __attribute__((ext_vector_type(8)));
typedef float f32x4 __attribute__((ext_vector_type(4)));
typedef int i32x4 __attribute__((ext_vector_type(4)));

#define LOG2E 1.44269504088896340736f

__device__ __forceinline__ float siluf(float x){ return x / (1.f + __expf(-x)); }
__device__ __forceinline__ float softplusf(float x){
  if (x > 20.f) return x;
  return log1pf(__expf(x));
}
// round-to-nearest-even f32 -> bf16 (finite inputs only)
__device__ __forceinline__ unsigned short f2bf(float f){
  unsigned int u = __builtin_bit_cast(unsigned int, f);
  u += 0x7fffu + ((u >> 16) & 1u);
  return (unsigned short)(u >> 16);
}
__device__ __forceinline__ float bf2f(unsigned short u){
  return __builtin_bit_cast(float, (unsigned int)u << 16);
}
template<typename CT>
__device__ __forceinline__ void st_ct(CT* p, float v){
  if constexpr (sizeof(CT)==2) *p = (CT)f2bf(v); else *p = (CT)v;
}

__device__ __forceinline__ void gl_lds16(const unsigned short* g, unsigned short* l){
  __builtin_amdgcn_global_load_lds(
      (const __attribute__((address_space(1))) void*)g,
      (__attribute__((address_space(3))) void*)l, 16, 0, 0);
}

// ---- one fused cast kernel: all weight/input casts, compile-time segments ----
#define SEG0 4096    // x            : NTOK*DM/1024
#define SEG1 8192    // ipw pair     : 2*(2*DI)*DM/1024
#define SEG2 512     // xpw pad pair : 2*128*DI/1024
#define SEG3 256     // dtw pair     : 2*DI*64/1024
#define SEG4 4096    // opw pair     : 2*DM*DI/1024
#define CAST_BLOCKS (SEG0+SEG1+SEG2+SEG3+SEG4)   // 17152

__device__ __forceinline__ void cast4(const float* src, unsigned short* dst){
  float4 v = *reinterpret_cast<const float4*>(src);
  ushort4 o; o.x=f2bf(v.x); o.y=f2bf(v.y); o.z=f2bf(v.z); o.w=f2bf(v.w);
  *reinterpret_cast<ushort4*>(dst) = o;
}

__global__ __launch_bounds__(256) void k_cast_all(
    const float* __restrict__ x,
    const float* __restrict__ ipw0, const float* __restrict__ ipw1,
    const float* __restrict__ xpw0, const float* __restrict__ xpw1,
    const float* __restrict__ dtw0, const float* __restrict__ dtw1,
    const float* __restrict__ opw0, const float* __restrict__ opw1,
    unsigned short* __restrict__ x_bf, unsigned short* __restrict__ w_bf,
    unsigned short* __restrict__ wpad, unsigned short* __restrict__ dtw_bf,
    unsigned short* __restrict__ outw){
  int bid = blockIdx.x;
  int ti = threadIdx.x*4;
  if (bid < SEG0){
    int i = bid*1024 + ti;
    cast4(x + i, x_bf + i);
  } else if (bid < SEG0+SEG1){
    int i = (bid-SEG0)*1024 + ti;
    const int n = (2*DI)*DM;
    const float* src = (i < n) ? ipw0 : ipw1;
    int off = (i < n) ? i : i - n;
    cast4(src + off, w_bf + i);
  } else if (bid < SEG0+SEG1+SEG2){
    int i = (bid-SEG0-SEG1)*1024 + ti;
    const int ntotal = 128*DI, nreal = 96*DI;
    int dir = i / ntotal;
    int r = i - dir*ntotal;
    if (r < nreal){
      cast4((dir ? xpw1 : xpw0) + r, wpad + i);
    } else {
      ushort4 z{0,0,0,0};
      *reinterpret_cast<ushort4*>(wpad + i) = z;
    }
  } else if (bid < SEG0+SEG1+SEG2+SEG3){
    int i = (bid-SEG0-SEG1-SEG2)*1024 + ti;
    const int n = DI*64;
    const float* src = (i < n) ? dtw0 : dtw1;
    int off = (i < n) ? i : i - n;
    cast4(src + off, dtw_bf + i);
  } else {
    int i = (bid-SEG0-SEG1-SEG2-SEG3)*1024 + ti;
    const int n = DM*DI;
    const float* src = (i < n) ? opw0 : opw1;
    int off = (i < n) ? i : i - n;
    cast4(src + off, outw + i);
  }
}

// ====== 256xBN tile, 8-wave, 4-slice ring pipeline (3-slice-ahead counted vmcnt) ======
// Slice = K=32 slab of A+B. Ring of 4 slices in LDS (128/96 KiB). Per phase s:
//   wait vmcnt(2*LPS)  [retires slice s; slices s+1,s+2 stay in flight]
//   barrier            [all waves done computing s-1 -> safe to overwrite ring[(s+3)&3]]
//   STAGE(s+3); COMPUTE(s)
// BN=256: LPS=4 gl_lds/slice, waves 2m x 4n(64-wide), acc[8][4].
// BN=128: LPS=3, waves 2m x 4n(32-wide), acc[8][2].
template<int NT, int BN, typename CT>
__global__ __launch_bounds__(512) void k_gemm256(
    const unsigned short* __restrict__ A, int lda, long long az,
    const unsigned short* __restrict__ Bw, int ldb, long long bz,
    CT* __restrict__ C, CT* __restrict__ C2, int nsplit,
    int ldc, long long cz){
  constexpr int KKSH = (BN==256) ? 16384 : 12288;   // shorts per slice (A 8192 + B)
  __shared__ unsigned short L[4*KKSH];
  const int dir = blockIdx.z;
  A  += (size_t)dir*az;
  Bw += (size_t)dir*bz;
  const int m0 = blockIdx.y*256;
  const int bn0 = blockIdx.x*BN;
  CT* Cout; int n0;
  if (bn0 < nsplit){ Cout = C; n0 = bn0; } else { Cout = C2; n0 = bn0 - nsplit; }
  Cout += (size_t)dir*cz;

  const int tid = threadIdx.x;
  const int w = tid >> 6, lane = tid & 63;
  // staging: each gl_lds covers 128 rows x 32 cols; thread row tid>>2, lds slot tid&3,
  // source slot XOR'd by (row>>1)&3 = (tid>>3)&3 (involution; inverse applied on read)
  const int rT = tid >> 2;                        // 0..127
  const int sG = (tid & 3) ^ ((tid >> 3) & 3);
  const unsigned short* srcA = A  + (size_t)(m0  + rT)*lda + sG*8;
  const unsigned short* srcB = Bw + (size_t)(bn0 + rT)*ldb + sG*8;
  unsigned short* const lw = &L[w*512];           // wave-uniform; HW adds lane*16B
  const int wmb = (w>>2)*128;
  const int wnb = (BN==256) ? (w&3)*64 : (w&3)*32;
  constexpr int NJ = (BN==256) ? 4 : 2;
  const int fr = lane & 15;
  const int sk = ((lane>>4) ^ ((fr>>1)&3))*8;     // unswizzled read slot (shorts)

  f32x4 acc[8][NJ] = {};

  auto STAGE = [&](int s){                        // slice index s in [0, 2*NT)
    const unsigned short* a_ = srcA + s*32;
    const unsigned short* b_ = srcB + s*32;
    unsigned short* l_ = lw + (s&3)*KKSH;
    gl_lds16(a_,                   l_);
    gl_lds16(a_ + (size_t)128*lda, l_ + 4096);
    gl_lds16(b_,                   l_ + 8192);
    if constexpr (BN==256)
      gl_lds16(b_ + (size_t)128*ldb, l_ + 8192 + 4096);
  };

  auto COMPUTE = [&](int s){
    const unsigned short* base = &L[(s&3)*KKSH];
    bf16x8 a[8];
#pragma unroll
    for (int i=0;i<8;i++)
      a[i] = *reinterpret_cast<const bf16x8*>(&base[(wmb + i*16 + fr)*32 + sk]);
    bf16x8 b0 = *reinterpret_cast<const bf16x8*>(&base[8192 + (wnb +  0 + fr)*32 + sk]);
    bf16x8 b1 = *reinterpret_cast<const bf16x8*>(&base[8192 + (wnb + 16 + fr)*32 + sk]);
    __builtin_amdgcn_s_setprio(1);
#pragma unroll
    for (int i=0;i<8;i++){
      acc[i][0] = __builtin_amdgcn_mfma_f32_16x16x32_bf16(a[i], b0, acc[i][0], 0,0,0);
      acc[i][1] = __builtin_amdgcn_mfma_f32_16x16x32_bf16(a[i], b1, acc[i][1], 0,0,0);
    }
    __builtin_amdgcn_s_setprio(0);
    if constexpr (BN==256){
      bf16x8 b2 = *reinterpret_cast<const bf16x8*>(&base[8192 + (wnb + 32 + fr)*32 + sk]);
      bf16x8 b3 = *reinterpret_cast<const bf16x8*>(&base[8192 + (wnb + 48 + fr)*32 + sk]);
      __builtin_amdgcn_s_setprio(1);
#pragma unroll
      for (int i=0;i<8;i++){
        acc[i][2] = __builtin_amdgcn_mfma_f32_16x16x32_bf16(a[i], b2, acc[i][2], 0,0,0);
        acc[i][3] = __builtin_amdgcn_mfma_f32_16x16x32_bf16(a[i], b3, acc[i][3], 0,0,0);
      }
      __builtin_amdgcn_s_setprio(0);
    }
  };

  auto WAIT2 = [&](){   // keep 2 slices (2*LPS loads) in flight
    if constexpr (BN==256) asm volatile("s_waitcnt vmcnt(8)" ::: "memory");
    else                   asm volatile("s_waitcnt vmcnt(6)" ::: "memory");
  };
  auto WAIT1 = [&](){   // keep 1 slice in flight
    if constexpr (BN==256) asm volatile("s_waitcnt vmcnt(4)" ::: "memory");
    else                   asm volatile("s_waitcnt vmcnt(3)" ::: "memory");
  };

  constexpr int S = 2*NT;
  STAGE(0); STAGE(1); STAGE(2);
#pragma unroll 4
  for (int s = 0; s < S-3; ++s){
    WAIT2();
    asm volatile("s_barrier" ::: "memory");
    STAGE(s+3);
    COMPUTE(s);
  }
  // epilogue: slices S-3, S-2, S-1 (no more stages)
  WAIT2();
  asm volatile("s_barrier" ::: "memory");
  COMPUTE(S-3);
  WAIT1();
  asm volatile("s_barrier" ::: "memory");
  COMPUTE(S-2);
  asm volatile("s_waitcnt vmcnt(0)" ::: "memory");
  asm volatile("s_barrier" ::: "memory");
  COMPUTE(S-1);

  const int er = (lane>>4)*4;
#pragma unroll
  for (int i=0;i<8;i++)
#pragma unroll
    for (int j=0;j<NJ;j++){
      int row = m0 + wmb + i*16 + er;
      int col = n0 + wnb + j*16 + fr;
      CT* cp = Cout + (size_t)row*ldc + col;
#pragma unroll
      for (int r=0;r<4;r++) st_ct(&cp[(size_t)r*ldc], acc[i][j][r]);
    }
}

// ---- 128x128 m97-structure GEMM (proven; xproj/dtproj) ----
template<int EPI, int KSPLIT, typename CT>
__global__ __launch_bounds__(256) void k_gemm_bt(
    const unsigned short* __restrict__ A, int lda, long long az,
    const unsigned short* __restrict__ Bw, int ldb, long long bz,
    CT* __restrict__ C, CT* __restrict__ C2, int nsplit,
    int ldc, long long cz, int coffz,
    int K, int coff,
    const float* __restrict__ bias0, const float* __restrict__ bias1){
  __shared__ unsigned short As[128*32];
  __shared__ unsigned short Bs[128*32];
  const int z = blockIdx.z;
  const int dirz = z / KSPLIT, kc = z - dirz*KSPLIT;
  A  += (size_t)dirz*az + (size_t)kc*K;
  Bw += (size_t)dirz*bz + (size_t)kc*K;
  const int bn0 = blockIdx.x*128;      // B-row base — never modified
  int n0 = bn0;                        // C-column base (post-split)
  if (bn0 >= nsplit){ C = C2; n0 = bn0 - nsplit; }
  C  += (size_t)z*cz;
  const int co = coff + dirz*coffz;
  const float* bias = dirz ? bias1 : bias0;

  const int t = threadIdx.x;
  const int m0 = blockIdx.y*128;
  const int lane = t & 63, w = t >> 6;
  const int wm = (w>>1)*64, wn = (w&1)*64;

  const int gr = lane >> 2;
  const int gslot = (lane & 3) ^ ((lane >> 3) & 3);
  const unsigned short* gA = A  + (size_t)(m0  + 32*w + gr)*lda + gslot*8;
  const unsigned short* gB = Bw + (size_t)(bn0 + 32*w + gr)*ldb + gslot*8;
  unsigned short* lA = &As[(32*w)*32];
  unsigned short* lB = &Bs[(32*w)*32];

  f32x4 acc[4][4] = {};
  const int fr = lane & 15;
  const int rslot = ((lane>>4) ^ ((lane>>1)&3))*8;

  for (int k0=0; k0<K; k0+=32){
    __syncthreads();
    gl_lds16(gA + k0, lA);
    gl_lds16(gA + (size_t)16*lda + k0, lA + 16*32);
    gl_lds16(gB + k0, lB);
    gl_lds16(gB + (size_t)16*ldb + k0, lB + 16*32);
    __syncthreads();
    bf16x8 af[4], bfr[4];
#pragma unroll
    for (int i=0;i<4;i++){
      af[i]  = *reinterpret_cast<const bf16x8*>(&As[(wm + i*16 + fr)*32 + rslot]);
      bfr[i] = *reinterpret_cast<const bf16x8*>(&Bs[(wn + i*16 + fr)*32 + rslot]);
    }
#pragma unroll
    for (int i=0;i<4;i++)
#pragma unroll
      for (int j=0;j<4;j++)
        acc[i][j] = __builtin_amdgcn_mfma_f32_16x16x32_bf16(af[i], bfr[j], acc[i][j], 0,0,0);
  }
  const int er = (lane>>4)*4;
#pragma unroll
  for (int i=0;i<4;i++)
#pragma unroll
    for (int j=0;j<4;j++){
      int row = m0 + wm + i*16 + er;
      int bcol = n0 + wn + j*16 + fr;
      CT* cp = C + (size_t)row*ldc + co + bcol;
      if (EPI == 1){
        float bv = bias[bcol];
#pragma unroll
        for (int r=0;r<4;r++) st_ct(&cp[(size_t)r*ldc], softplusf(acc[i][j][r] + bv));
      } else {
#pragma unroll
        for (int r=0;r<4;r++) st_ct(&cp[(size_t)r*ldc], acc[i][j][r]);
      }
    }
}

// ---- vectorized depthwise causal conv1d + bias + silu (8ch x 4tok per thread) ----
__global__ __launch_bounds__(256) void k_conv_silu(const unsigned short* __restrict__ xpre,
    const float* __restrict__ cw0, const float* __restrict__ cw1,
    const float* __restrict__ cb0, const float* __restrict__ cb1,
    unsigned short* __restrict__ xi_bf){
  const int dir = blockIdx.z;
  const int d0 = threadIdx.x*8;
  const int tok0 = blockIdx.x*4;
  const int b = tok0 >> 11;
  const int t0 = tok0 & (LL-1);
  const float* cw = dir ? cw1 : cw0;
  const float* cb = dir ? cb1 : cb0;
  const unsigned short* xpd = xpre + (size_t)dir*NTOK*DI;
  unsigned short* outp = xi_bf + (size_t)dir*NTOK*DI;

  float wv[4][8];
#pragma unroll
  for (int c=0;c<8;c++){
    float4 w = *reinterpret_cast<const float4*>(cw + (size_t)(d0+c)*4);
    wv[0][c]=w.x; wv[1][c]=w.y; wv[2][c]=w.z; wv[3][c]=w.w;
  }
  float bv[8];
  {
    float4 b0 = *reinterpret_cast<const float4*>(cb + d0);
    float4 b1 = *reinterpret_cast<const float4*>(cb + d0 + 4);
    bv[0]=b0.x; bv[1]=b0.y; bv[2]=b0.z; bv[3]=b0.w;
    bv[4]=b1.x; bv[5]=b1.y; bv[6]=b1.z; bv[7]=b1.w;
  }
  const int rbase = t0 + (dir ? 0 : -3);
  float rows[7][8];
#pragma unroll
  for (int i=0;i<7;i++){
    int r = rbase + i;
    if (r >= 0 && r < LL){
      union { i32x4 v; unsigned short u[8]; } x;
      x.v = *reinterpret_cast<const i32x4*>(xpd + ((size_t)b*LL + r)*DI + d0);
#pragma unroll
      for (int c=0;c<8;c++) rows[i][c] = bf2f(x.u[c]);
    } else {
#pragma unroll
      for (int c=0;c<8;c++) rows[i][c] = 0.f;
    }
  }
#pragma unroll
  for (int j=0;j<4;j++){
    union { i32x4 v; unsigned short u[8]; } o;
#pragma unroll
    for (int c=0;c<8;c++){
      float acc = bv[c];
#pragma unroll
      for (int m=0;m<4;m++){
        float w = dir ? wv[3-m][c] : wv[m][c];
        acc += w * rows[j+m][c];
      }
      o.u[c] = f2bf(siluf(acc));
    }
    *reinterpret_cast<i32x4*>(outp + ((size_t)(tok0+j))*DI + d0) = o.v;
  }
}

// reduce split-K partials -> xdbl f32 [2][NTOK][96]; bf16 of cols 0..63
__global__ __launch_bounds__(256) void k_xred(const float* __restrict__ part,
    float* __restrict__ xdbl, unsigned short* __restrict__ xdbl_bf){
  int idx = blockIdx.x*256 + threadIdx.x;
  if (idx >= 2*NTOK*96) return;
  int dir = idx / (NTOK*96);
  int rem = idx - dir*(NTOK*96);
  int tok = rem / 96, j = rem - tok*96;
  const float* pd = part + (size_t)dir*4*NTOK*128;
  const size_t czs = (size_t)NTOK*128;
  size_t o = (size_t)tok*128 + j;
  float v = pd[o] + pd[czs + o] + pd[2*czs + o] + pd[3*czs + o];
  xdbl[(size_t)dir*NTOK*96 + (size_t)tok*96 + j] = v;
  if (j < 64) xdbl_bf[(size_t)dir*NTOK*64 + (size_t)tok*64 + j] = f2bf(v);
}

// build dA[0..15] = q^(n+1) with a log-depth power tree (15 muls, depth 4)
__device__ __forceinline__ void powtree(float q, float* dA){
  dA[0]=q;
  dA[1]=dA[0]*dA[0];
  dA[2]=dA[1]*dA[0];
  dA[3]=dA[1]*dA[1];
  dA[4]=dA[3]*dA[0];
  dA[5]=dA[3]*dA[1];
  dA[6]=dA[3]*dA[2];
  dA[7]=dA[3]*dA[3];
#pragma unroll
  for (int n=8;n<16;n++) dA[n]=dA[7]*dA[n-8];
}
// check Alog2[n] ~= (n+1)*Alog2[0]  (S4D-real init); rel tol 1e-5
__device__ __forceinline__ bool chk_struct(const float* Alog2){
  bool ok = true;
  float a0 = Alog2[0];
#pragma unroll
  for (int n=1;n<16;n++){
    float e = a0*(float)(n+1);
    ok = ok && (fabsf(Alog2[n]-e) <= 1e-5f*fabsf(e) + 1e-12f);
  }
  return ok;
}

// ---- chunked selective scan (NC=64, CL=32), lane = channel, h[16] in regs ----
__global__ __launch_bounds__(256) void k_scan_p1(const unsigned short* __restrict__ u,
    const unsigned short* __restrict__ dt, const float* __restrict__ xdbl,
    const float* __restrict__ A_log0, const float* __restrict__ A_log1,
    float* __restrict__ hloc, float* __restrict__ dtsum){
  __shared__ float Bs[CL*16];
  const int dir = blockIdx.z;
  u    += (size_t)dir*NTOK*DI;
  dt   += (size_t)dir*NTOK*DI;
  xdbl += (size_t)dir*NTOK*96;
  const float* A_log = dir ? A_log1 : A_log0;
  const int tid = threadIdx.x;
  const int ch = blockIdx.x*256 + tid;
  const int c = blockIdx.y;
  const int b = (blockIdx.x*256) >> 11;
  const int d = ch & (DI-1);
  for (int i = tid; i < CL*16; i += 256){
    int s = i >> 4, j = i & 15;
    int sg = c*CL + s;
    int tt = dir ? (LL-1-sg) : sg;
    Bs[i] = xdbl[((size_t)b*LL + tt)*96 + 64 + j];
  }
  float Alog2[16];
  {
    const float4* ap = reinterpret_cast<const float4*>(A_log + (size_t)d*16);
#pragma unroll
    for (int q=0;q<4;q++){
      float4 v = ap[q];
      Alog2[q*4+0] = -__expf(v.x)*LOG2E;
      Alog2[q*4+1] = -__expf(v.y)*LOG2E;
      Alog2[q*4+2] = -__expf(v.z)*LOG2E;
      Alog2[q*4+3] = -__expf(v.w)*LOG2E;
    }
  }
  const bool structured = chk_struct(Alog2);
  __syncthreads();
  float h[16];
#pragma unroll
  for (int n=0;n<16;n++) h[n]=0.f;
  float dts = 0.f;
  int tok0 = b*LL + (dir ? (LL-1-c*CL) : c*CL);
  const unsigned short* up = u + (size_t)tok0*DI + d;
  const unsigned short* dtp = dt + (size_t)tok0*DI + d;
  const ptrdiff_t stp = dir ? -(ptrdiff_t)DI : (ptrdiff_t)DI;
  if (structured){
    const float a0 = Alog2[0];
#pragma unroll 2
    for (int s=0; s<CL; s++){
      float uv  = bf2f(*up); up += stp;
      float dtv = bf2f(*dtp); dtp += stp;
      float dtu = dtv*uv;
      dts += dtv;
      const f32x4* br = reinterpret_cast<const f32x4*>(&Bs[s*16]);
      f32x4 B0=br[0], B1=br[1], B2=br[2], B3=br[3];
      float dA[16];
      powtree(__builtin_amdgcn_exp2f(dtv*a0), dA);
#pragma unroll
      for (int n=0;n<16;n++){
        float Bv = (n<4)?B0[n&3] : (n<8)?B1[n&3] : (n<12)?B2[n&3] : B3[n&3];
        h[n] = dA[n]*h[n] + dtu*Bv;
      }
    }
  } else {
#pragma unroll 2
    for (int s=0; s<CL; s++){
      float uv  = bf2f(*up); up += stp;
      float dtv = bf2f(*dtp); dtp += stp;
      float dtu = dtv*uv;
      dts += dtv;
      const f32x4* br = reinterpret_cast<const f32x4*>(&Bs[s*16]);
      f32x4 B0=br[0], B1=br[1], B2=br[2], B3=br[3];
#pragma unroll
      for (int n=0;n<16;n++){
        float dA = __builtin_amdgcn_exp2f(dtv*Alog2[n]);
        float Bv = (n<4)?B0[n&3] : (n<8)?B1[n&3] : (n<12)?B2[n&3] : B3[n&3];
        h[n] = dA*h[n] + dtu*Bv;
      }
    }
  }
  float* hp = hloc + (((size_t)(dir*NC + c)*NCH + ch))*16;
#pragma unroll
  for (int q=0;q<4;q++)
    *reinterpret_cast<f32x4*>(hp + q*4) = f32x4{h[q*4],h[q*4+1],h[q*4+2],h[q*4+3]};
  dtsum[(size_t)(dir*NC + c)*NCH + ch] = dts;
}

// combine: per (dir,ch,n); pa = exp2(dtsum*Alog2[n]); hstart written over hloc
__global__ __launch_bounds__(256) void k_scan_comb(float* __restrict__ hloc,
    const float* __restrict__ dtsum,
    const float* __restrict__ A_log0, const float* __restrict__ A_log1){
  int i = blockIdx.x*256 + threadIdx.x;   // covers 2*NCH*16
  int dir = i / (NCH*16);
  int j = i - dir*(NCH*16);
  int ch = j >> 4, n = j & 15;
  int d = ch & (DI-1);
  const float* A_log = dir ? A_log1 : A_log0;
  float Alog2 = -__expf(A_log[(size_t)d*16 + n])*LOG2E;
  float hs = 0.f;
#pragma unroll 4
  for (int c=0; c<NC; c++){
    size_t base = (size_t)(dir*NC + c)*NCH + ch;
    float pa = __builtin_amdgcn_exp2f(dtsum[base]*Alog2);
    size_t idx = base*16 + n;
    float h = hloc[idx];
    hloc[idx] = hs;
    hs = pa*hs + h;
  }
}

// pass 2: rescan from hstart(=hloc); fused gate: g = bf16(y*silu(z)) over u
__global__ __launch_bounds__(256) void k_scan_p2(unsigned short* __restrict__ uy,
    const unsigned short* __restrict__ dt, const float* __restrict__ xdbl,
    const unsigned short* __restrict__ zbuf,
    const float* __restrict__ A_log0, const float* __restrict__ A_log1,
    const float* __restrict__ Dp0, const float* __restrict__ Dp1,
    const float* __restrict__ hstart){
  __shared__ float BCs[CL*32];
  const int dir = blockIdx.z;
  uy   += (size_t)dir*NTOK*DI;
  dt   += (size_t)dir*NTOK*DI;
  zbuf += (size_t)dir*NTOK*DI;
  xdbl += (size_t)dir*NTOK*96;
  const float* A_log = dir ? A_log1 : A_log0;
  const float* Dp = dir ? Dp1 : Dp0;
  const int tid = threadIdx.x;
  const int ch = blockIdx.x*256 + tid;
  const int c = blockIdx.y;
  const int b = (blockIdx.x*256) >> 11;
  const int d = ch & (DI-1);
  for (int i = tid; i < CL*32; i += 256){
    int s = i >> 5, j = i & 31;
    int sg = c*CL + s;
    int tt = dir ? (LL-1-sg) : sg;
    BCs[i] = xdbl[((size_t)b*LL + tt)*96 + 64 + j];
  }
  float Alog2[16];
  {
    const float4* ap = reinterpret_cast<const float4*>(A_log + (size_t)d*16);
#pragma unroll
    for (int q=0;q<4;q++){
      float4 v = ap[q];
      Alog2[q*4+0] = -__expf(v.x)*LOG2E;
      Alog2[q*4+1] = -__expf(v.y)*LOG2E;
      Alog2[q*4+2] = -__expf(v.z)*LOG2E;
      Alog2[q*4+3] = -__expf(v.w)*LOG2E;
    }
  }
  const bool structured = chk_struct(Alog2);
  float h[16];
  {
    const float* hp = hstart + (((size_t)(dir*NC + c)*NCH + ch))*16;
#pragma unroll
    for (int q=0;q<4;q++){
      f32x4 v = *reinterpret_cast<const f32x4*>(hp + q*4);
      h[q*4]=v[0]; h[q*4+1]=v[1]; h[q*4+2]=v[2]; h[q*4+3]=v[3];
    }
  }
  const float Dval = Dp[d];
  __syncthreads();
  int tok0 = b*LL + (dir ? (LL-1-c*CL) : c*CL);
  unsigned short* up = uy + (size_t)tok0*DI + d;
  const unsigned short* zp = zbuf + (size_t)tok0*DI + d;
  const unsigned short* dtp = dt + (size_t)tok0*DI + d;
  const ptrdiff_t stp = dir ? -(ptrdiff_t)DI : (ptrdiff_t)DI;
  if (structured){
    const float a0 = Alog2[0];
#pragma unroll 2
    for (int s=0; s<CL; s++){
      float uv  = bf2f(*up);
      float zv  = bf2f(*zp); zp += stp;
      float dtv = bf2f(*dtp); dtp += stp;
      float dtu = dtv*uv;
      float y = Dval*uv;
      const f32x4* br = reinterpret_cast<const f32x4*>(&BCs[s*32]);
      f32x4 B0=br[0], B1=br[1], B2=br[2], B3=br[3];
      f32x4 C0=br[4], C1=br[5], C2=br[6], C3=br[7];
      float dA[16];
      powtree(__builtin_amdgcn_exp2f(dtv*a0), dA);
#pragma unroll
      for (int n=0;n<16;n++){
        float Bv = (n<4)?B0[n&3] : (n<8)?B1[n&3] : (n<12)?B2[n&3] : B3[n&3];
        float Cv = (n<4)?C0[n&3] : (n<8)?C1[n&3] : (n<12)?C2[n&3] : C3[n&3];
        h[n] = dA[n]*h[n] + dtu*Bv;
        y += h[n]*Cv;
      }
      *up = f2bf(y * siluf(zv)); up += stp;
    }
  } else {
#pragma unroll 2
    for (int s=0; s<CL; s++){
      float uv  = bf2f(*up);
      float zv  = bf2f(*zp); zp += stp;
      float dtv = bf2f(*dtp); dtp += stp;
      float dtu = dtv*uv;
      float y = Dval*uv;
      const f32x4* br = reinterpret_cast<const f32x4*>(&BCs[s*32]);
      f32x4 B0=br[0], B1=br[1], B2=br[2], B3=br[3];
      f32x4 C0=br[4], C1=br[5], C2=br[6], C3=br[7];
#pragma unroll
      for (int n=0;n<16;n++){
        float dA = __builtin_amdgcn_exp2f(dtv*Alog2[n]);
        float Bv = (n<4)?B0[n&3] : (n<8)?B1[n&3] : (n<12)?B2[n&3] : B3[n&3];
        float Cv = (n<4)?C0[n&3] : (n<8)?C1[n&3] : (n<12)?C2[n&3] : C3[n&3];
        h[n] = dA*h[n] + dtu*Bv;
        y += h[n]*Cv;
      }
      *up = f2bf(y * siluf(zv)); up += stp;
    }
  }
}

extern "C" void kernel_launch(void* const* d_in, const int* in_sizes, int n_in,
                              void* d_out, int out_size, void* d_ws, size_t ws_size,
                              hipStream_t stream){
  (void)in_sizes; (void)n_in; (void)out_size; (void)ws_size;
  const float* x = (const float*)d_in[0];
  const float* ipw[2], *cw[2], *cb[2], *xpw[2], *dtw_[2], *dtb[2], *Alog[2], *Dp[2], *opw[2];
  for (int dir=0; dir<2; dir++){
    ipw[dir]  = (const float*)d_in[1 + dir*9 + 0];
    cw[dir]   = (const float*)d_in[1 + dir*9 + 1];
    cb[dir]   = (const float*)d_in[1 + dir*9 + 2];
    xpw[dir]  = (const float*)d_in[1 + dir*9 + 3];
    dtw_[dir] = (const float*)d_in[1 + dir*9 + 4];
    dtb[dir]  = (const float*)d_in[1 + dir*9 + 5];
    Alog[dir] = (const float*)d_in[1 + dir*9 + 6];
    Dp[dir]   = (const float*)d_in[1 + dir*9 + 7];
    opw[dir]  = (const float*)d_in[1 + dir*9 + 8];
  }
  char* p = (char*)d_ws;
  auto alloc = [&](size_t bytes)->void*{ void* r=(void*)p; p += (bytes+255)&~(size_t)255; return r; };
  // sequential allocations (~166 MiB total)
  unsigned short* x_bf   = (unsigned short*)alloc((size_t)NTOK*DM*2);        // [0,8) MiB
  unsigned short* w_bf   = (unsigned short*)alloc((size_t)2*(2*DI)*DM*2);    // [8,24) MiB
  float* part            = (float*)w_bf;                                      // alias
  unsigned short* xpre   = (unsigned short*)alloc((size_t)2*NTOK*DI*2);      // [24,56) MiB
  unsigned short* zbuf   = (unsigned short*)alloc((size_t)2*NTOK*DI*2);      // 32 MiB
  unsigned short* xi_bf  = (unsigned short*)alloc((size_t)2*NTOK*DI*2);      // 32 MiB (u, then g)
  float* xdbl            = (float*)alloc((size_t)2*NTOK*96*4);               // 3 MiB
  unsigned short* xdbl_bf= (unsigned short*)alloc((size_t)2*NTOK*64*2);      // 1 MiB
  unsigned short* dt_bf  = (unsigned short*)alloc((size_t)2*NTOK*DI*2);      // 32 MiB
  unsigned short* wpad   = (unsigned short*)alloc((size_t)2*128*DI*2);       // 1 MiB
  unsigned short* dtw_bf = (unsigned short*)alloc((size_t)2*DI*64*2);        // 0.5 MiB
  unsigned short* outw   = (unsigned short*)alloc((size_t)2*DM*DI*2);        // 8 MiB
  // scan temporaries overlay the dead-by-scan-time region [0,56) MiB
  float* hloc  = (float*)d_ws;                                    // [0,32) MiB
  float* dtsum = (float*)((char*)d_ws + (size_t)32*1024*1024);    // [32,34) MiB

  // all casts in one dispatch
  k_cast_all<<<CAST_BLOCKS, 256, 0, stream>>>(
      x, ipw[0], ipw[1], xpw[0], xpw[1], dtw_[0], dtw_[1], opw[0], opw[1],
      x_bf, w_bf, wpad, dtw_bf, outw);

  // in_proj: 256^2 ring-pipelined GEMM; cols [0,2048)->xpre, [2048,4096)->zbuf
  k_gemm256<16,256,unsigned short><<<dim3(16,16,2), 512, 0, stream>>>(
      x_bf, DM, 0, w_bf, DM, (long long)(2*DI)*DM,
      xpre, zbuf, DI, DI, (long long)NTOK*DI);
  // conv + silu -> u (bf16), vectorized 8ch x 4tok per thread
  k_conv_silu<<<dim3(NTOK/4,1,2), 256, 0, stream>>>(xpre, cw[0], cw[1], cb[0], cb[1], xi_bf);
  // xproj (split-K=4, both dirs): part[z] = u_z @ wpad_z^T   (part aliases w_bf)
  k_gemm_bt<0,4,float><<<dim3(1,32,8), 256, 0, stream>>>(
      xi_bf, DI, (long long)NTOK*DI, wpad, DI, (long long)128*DI,
      part, part, 1<<30, 128, (long long)NTOK*128, 0, 512, 0, nullptr, nullptr);
  k_xred<<<(2*NTOK*96+255)/256, 256, 0, stream>>>(part, xdbl, xdbl_bf);
  // dt = softplus(xdbl[:, :64] @ dtw^T + b), stored bf16
  k_gemm_bt<1,1,unsigned short><<<dim3(16,32,2), 256, 0, stream>>>(
      xdbl_bf, 64, (long long)NTOK*64, dtw_bf, 64, (long long)DI*64,
      dt_bf, dt_bf, 1<<30, DI, (long long)NTOK*DI, 0, 64, 0, dtb[0], dtb[1]);
  // chunked scan (NC=64): hloc/dtsum overlay dead region
  k_scan_p1<<<dim3(NCH/256, NC, 2), 256, 0, stream>>>(xi_bf, dt_bf, xdbl,
      Alog[0], Alog[1], hloc, dtsum);
  k_scan_comb<<<2*NCH*16/256, 256, 0, stream>>>(hloc, dtsum, Alog[0], Alog[1]);
  k_scan_p2<<<dim3(NCH/256, NC, 2), 256, 0, stream>>>(xi_bf, dt_bf, xdbl, zbuf,
      Alog[0], Alog[1], Dp[0], Dp[1], hloc);
  // out = g @ out_proj^T on the ring-pipelined 256x128 kernel; dir offsets cols by DM
  k_gemm256<32,128,float><<<dim3(8,16,2), 512, 0, stream>>>(
      xi_bf, DI, (long long)NTOK*DI, outw, DI, (long long)DM*DI,
      (float*)d_out, (float*)d_out, 1<<30, 2*DM, (long long)DM);
}

// Round 20
// 349.464 us; speedup vs baseline: 1.0113x; 1.0113x over previous
//
#include <hip/hip_runtime.h>

#define BB 2
#define LL 2048
#define DM 1024
#define DI 2048
#define NTOK (BB*LL)   // 4096
#define NC 64
#define CL (LL/NC)     // 32
#define NCH (BB*DI)    // 4096 channels total

typedef __bf16 bf16x8 __attribute__((ext_vector_type(8)));
typedef float f32x4 __attribute__((ext_vector_type(4)));
typedef int i32x4 __attribute__((ext_vector_type(4)));

#define LOG2E 1.44269504088896340736f

__device__ __forceinline__ float siluf(float x){ return x / (1.f + __expf(-x)); }
__device__ __forceinline__ float softplusf(float x){
  if (x > 20.f) return x;
  return log1pf(__expf(x));
}
// round-to-nearest-even f32 -> bf16 (finite inputs only)
__device__ __forceinline__ unsigned short f2bf(float f){
  unsigned int u = __builtin_bit_cast(unsigned int, f);
  u += 0x7fffu + ((u >> 16) & 1u);
  return (unsigned short)(u >> 16);
}
__device__ __forceinline__ float bf2f(unsigned short u){
  return __builtin_bit_cast(float, (unsigned int)u << 16);
}
template<typename CT>
__device__ __forceinline__ void st_ct(CT* p, float v){
  if constexpr (sizeof(CT)==2) *p = (CT)f2bf(v); else *p = (CT)v;
}

__device__ __forceinline__ void gl_lds16(const unsigned short* g, unsigned short* l){
  __builtin_amdgcn_global_load_lds(
      (const __attribute__((address_space(1))) void*)g,
      (__attribute__((address_space(3))) void*)l, 16, 0, 0);
}

// ---- one fused cast kernel: all weight/input casts, compile-time segments ----
#define SEG0 4096    // x            : NTOK*DM/1024
#define SEG1 8192    // ipw pair     : 2*(2*DI)*DM/1024
#define SEG2 512     // xpw pad pair : 2*128*DI/1024
#define SEG3 256     // dtw pair     : 2*DI*64/1024
#define SEG4 4096    // opw pair     : 2*DM*DI/1024
#define CAST_BLOCKS (SEG0+SEG1+SEG2+SEG3+SEG4)   // 17152

__device__ __forceinline__ void cast4(const float* src, unsigned short* dst){
  float4 v = *reinterpret_cast<const float4*>(src);
  ushort4 o; o.x=f2bf(v.x); o.y=f2bf(v.y); o.z=f2bf(v.z); o.w=f2bf(v.w);
  *reinterpret_cast<ushort4*>(dst) = o;
}

__global__ __launch_bounds__(256) void k_cast_all(
    const float* __restrict__ x,
    const float* __restrict__ ipw0, const float* __restrict__ ipw1,
    const float* __restrict__ xpw0, const float* __restrict__ xpw1,
    const float* __restrict__ dtw0, const float* __restrict__ dtw1,
    const float* __restrict__ opw0, const float* __restrict__ opw1,
    unsigned short* __restrict__ x_bf, unsigned short* __restrict__ w_bf,
    unsigned short* __restrict__ wpad, unsigned short* __restrict__ dtw_bf,
    unsigned short* __restrict__ outw){
  int bid = blockIdx.x;
  int ti = threadIdx.x*4;
  if (bid < SEG0){
    int i = bid*1024 + ti;
    cast4(x + i, x_bf + i);
  } else if (bid < SEG0+SEG1){
    int i = (bid-SEG0)*1024 + ti;
    const int n = (2*DI)*DM;
    const float* src = (i < n) ? ipw0 : ipw1;
    int off = (i < n) ? i : i - n;
    cast4(src + off, w_bf + i);
  } else if (bid < SEG0+SEG1+SEG2){
    int i = (bid-SEG0-SEG1)*1024 + ti;
    const int ntotal = 128*DI, nreal = 96*DI;
    int dir = i / ntotal;
    int r = i - dir*ntotal;
    if (r < nreal){
      cast4((dir ? xpw1 : xpw0) + r, wpad + i);
    } else {
      ushort4 z{0,0,0,0};
      *reinterpret_cast<ushort4*>(wpad + i) = z;
    }
  } else if (bid < SEG0+SEG1+SEG2+SEG3){
    int i = (bid-SEG0-SEG1-SEG2)*1024 + ti;
    const int n = DI*64;
    const float* src = (i < n) ? dtw0 : dtw1;
    int off = (i < n) ? i : i - n;
    cast4(src + off, dtw_bf + i);
  } else {
    int i = (bid-SEG0-SEG1-SEG2-SEG3)*1024 + ti;
    const int n = DM*DI;
    const float* src = (i < n) ? opw0 : opw1;
    int off = (i < n) ? i : i - n;
    cast4(src + off, outw + i);
  }
}

// ====== 256xBN tile, 8-wave, 4-slice ring pipeline + split-phase compute ======
// Phase s: wait vmcnt(2*LPS); barrier; STAGE(s+3); issue frag ds_reads;
//          barrier; lgkmcnt(0); sched_barrier; setprio+MFMA cluster.
// The mid-phase barrier makes the MFMA cluster pure-register so other waves'
// MFMA covers this wave's LDS latency (m201 pattern).
template<int NT, int BN, typename CT>
__global__ __launch_bounds__(512) void k_gemm256(
    const unsigned short* __restrict__ A, int lda, long long az,
    const unsigned short* __restrict__ Bw, int ldb, long long bz,
    CT* __restrict__ C, CT* __restrict__ C2, int nsplit,
    int ldc, long long cz){
  constexpr int KKSH = (BN==256) ? 16384 : 12288;   // shorts per slice (A 8192 + B)
  __shared__ unsigned short L[4*KKSH];
  const int dir = blockIdx.z;
  A  += (size_t)dir*az;
  Bw += (size_t)dir*bz;
  const int m0 = blockIdx.y*256;
  const int bn0 = blockIdx.x*BN;
  CT* Cout; int n0;
  if (bn0 < nsplit){ Cout = C; n0 = bn0; } else { Cout = C2; n0 = bn0 - nsplit; }
  Cout += (size_t)dir*cz;

  const int tid = threadIdx.x;
  const int w = tid >> 6, lane = tid & 63;
  const int rT = tid >> 2;                        // 0..127
  const int sG = (tid & 3) ^ ((tid >> 3) & 3);
  const unsigned short* srcA = A  + (size_t)(m0  + rT)*lda + sG*8;
  const unsigned short* srcB = Bw + (size_t)(bn0 + rT)*ldb + sG*8;
  unsigned short* const lw = &L[w*512];           // wave-uniform; HW adds lane*16B
  const int wmb = (w>>2)*128;
  const int wnb = (BN==256) ? (w&3)*64 : (w&3)*32;
  constexpr int NJ = (BN==256) ? 4 : 2;
  const int fr = lane & 15;
  const int sk = ((lane>>4) ^ ((fr>>1)&3))*8;     // unswizzled read slot (shorts)

  f32x4 acc[8][NJ] = {};

  auto STAGE = [&](int s){                        // slice index s in [0, 2*NT)
    const unsigned short* a_ = srcA + s*32;
    const unsigned short* b_ = srcB + s*32;
    unsigned short* l_ = lw + (s&3)*KKSH;
    gl_lds16(a_,                   l_);
    gl_lds16(a_ + (size_t)128*lda, l_ + 4096);
    gl_lds16(b_,                   l_ + 8192);
    if constexpr (BN==256)
      gl_lds16(b_ + (size_t)128*ldb, l_ + 8192 + 4096);
  };

  auto COMPUTE = [&](int s){
    const unsigned short* base = &L[(s&3)*KKSH];
    bf16x8 a[8], b[NJ];
#pragma unroll
    for (int i=0;i<8;i++)
      a[i] = *reinterpret_cast<const bf16x8*>(&base[(wmb + i*16 + fr)*32 + sk]);
#pragma unroll
    for (int j=0;j<NJ;j++)
      b[j] = *reinterpret_cast<const bf16x8*>(&base[8192 + (wnb + j*16 + fr)*32 + sk]);
    // split-phase: reads issued; barrier so all waves' MFMA clusters overlap
    asm volatile("s_barrier" ::: "memory");
    asm volatile("s_waitcnt lgkmcnt(0)" ::: "memory");
    __builtin_amdgcn_sched_barrier(0);
    __builtin_amdgcn_s_setprio(1);
#pragma unroll
    for (int i=0;i<8;i++)
#pragma unroll
      for (int j=0;j<NJ;j++)
        acc[i][j] = __builtin_amdgcn_mfma_f32_16x16x32_bf16(a[i], b[j], acc[i][j], 0,0,0);
    __builtin_amdgcn_s_setprio(0);
  };

  auto WAIT2 = [&](){   // keep 2 slices (2*LPS loads) in flight
    if constexpr (BN==256) asm volatile("s_waitcnt vmcnt(8)" ::: "memory");
    else                   asm volatile("s_waitcnt vmcnt(6)" ::: "memory");
  };
  auto WAIT1 = [&](){   // keep 1 slice in flight
    if constexpr (BN==256) asm volatile("s_waitcnt vmcnt(4)" ::: "memory");
    else                   asm volatile("s_waitcnt vmcnt(3)" ::: "memory");
  };

  constexpr int S = 2*NT;
  STAGE(0); STAGE(1); STAGE(2);
#pragma unroll 4
  for (int s = 0; s < S-3; ++s){
    WAIT2();
    asm volatile("s_barrier" ::: "memory");
    STAGE(s+3);
    COMPUTE(s);
  }
  // epilogue: slices S-3, S-2, S-1 (no more stages)
  WAIT2();
  asm volatile("s_barrier" ::: "memory");
  COMPUTE(S-3);
  WAIT1();
  asm volatile("s_barrier" ::: "memory");
  COMPUTE(S-2);
  asm volatile("s_waitcnt vmcnt(0)" ::: "memory");
  asm volatile("s_barrier" ::: "memory");
  COMPUTE(S-1);

  const int er = (lane>>4)*4;
#pragma unroll
  for (int i=0;i<8;i++)
#pragma unroll
    for (int j=0;j<NJ;j++){
      int row = m0 + wmb + i*16 + er;
      int col = n0 + wnb + j*16 + fr;
      CT* cp = Cout + (size_t)row*ldc + col;
#pragma unroll
      for (int r=0;r<4;r++) st_ct(&cp[(size_t)r*ldc], acc[i][j][r]);
    }
}

// ---- 128x128 m97-structure GEMM (proven; xproj/dtproj) ----
template<int EPI, int KSPLIT, typename CT>
__global__ __launch_bounds__(256) void k_gemm_bt(
    const unsigned short* __restrict__ A, int lda, long long az,
    const unsigned short* __restrict__ Bw, int ldb, long long bz,
    CT* __restrict__ C, CT* __restrict__ C2, int nsplit,
    int ldc, long long cz, int coffz,
    int K, int coff,
    const float* __restrict__ bias0, const float* __restrict__ bias1){
  __shared__ unsigned short As[128*32];
  __shared__ unsigned short Bs[128*32];
  const int z = blockIdx.z;
  const int dirz = z / KSPLIT, kc = z - dirz*KSPLIT;
  A  += (size_t)dirz*az + (size_t)kc*K;
  Bw += (size_t)dirz*bz + (size_t)kc*K;
  const int bn0 = blockIdx.x*128;      // B-row base — never modified
  int n0 = bn0;                        // C-column base (post-split)
  if (bn0 >= nsplit){ C = C2; n0 = bn0 - nsplit; }
  C  += (size_t)z*cz;
  const int co = coff + dirz*coffz;
  const float* bias = dirz ? bias1 : bias0;

  const int t = threadIdx.x;
  const int m0 = blockIdx.y*128;
  const int lane = t & 63, w = t >> 6;
  const int wm = (w>>1)*64, wn = (w&1)*64;

  const int gr = lane >> 2;
  const int gslot = (lane & 3) ^ ((lane >> 3) & 3);
  const unsigned short* gA = A  + (size_t)(m0  + 32*w + gr)*lda + gslot*8;
  const unsigned short* gB = Bw + (size_t)(bn0 + 32*w + gr)*ldb + gslot*8;
  unsigned short* lA = &As[(32*w)*32];
  unsigned short* lB = &Bs[(32*w)*32];

  f32x4 acc[4][4] = {};
  const int fr = lane & 15;
  const int rslot = ((lane>>4) ^ ((lane>>1)&3))*8;

  for (int k0=0; k0<K; k0+=32){
    __syncthreads();
    gl_lds16(gA + k0, lA);
    gl_lds16(gA + (size_t)16*lda + k0, lA + 16*32);
    gl_lds16(gB + k0, lB);
    gl_lds16(gB + (size_t)16*ldb + k0, lB + 16*32);
    __syncthreads();
    bf16x8 af[4], bfr[4];
#pragma unroll
    for (int i=0;i<4;i++){
      af[i]  = *reinterpret_cast<const bf16x8*>(&As[(wm + i*16 + fr)*32 + rslot]);
      bfr[i] = *reinterpret_cast<const bf16x8*>(&Bs[(wn + i*16 + fr)*32 + rslot]);
    }
#pragma unroll
    for (int i=0;i<4;i++)
#pragma unroll
      for (int j=0;j<4;j++)
        acc[i][j] = __builtin_amdgcn_mfma_f32_16x16x32_bf16(af[i], bfr[j], acc[i][j], 0,0,0);
  }
  const int er = (lane>>4)*4;
#pragma unroll
  for (int i=0;i<4;i++)
#pragma unroll
    for (int j=0;j<4;j++){
      int row = m0 + wm + i*16 + er;
      int bcol = n0 + wn + j*16 + fr;
      CT* cp = C + (size_t)row*ldc + co + bcol;
      if (EPI == 1){
        float bv = bias[bcol];
#pragma unroll
        for (int r=0;r<4;r++) st_ct(&cp[(size_t)r*ldc], softplusf(acc[i][j][r] + bv));
      } else {
#pragma unroll
        for (int r=0;r<4;r++) st_ct(&cp[(size_t)r*ldc], acc[i][j][r]);
      }
    }
}

// ---- vectorized depthwise causal conv1d + bias + silu (8ch x 4tok per thread) ----
__global__ __launch_bounds__(256) void k_conv_silu(const unsigned short* __restrict__ xpre,
    const float* __restrict__ cw0, const float* __restrict__ cw1,
    const float* __restrict__ cb0, const float* __restrict__ cb1,
    unsigned short* __restrict__ xi_bf){
  const int dir = blockIdx.z;
  const int d0 = threadIdx.x*8;
  const int tok0 = blockIdx.x*4;
  const int b = tok0 >> 11;
  const int t0 = tok0 & (LL-1);
  const float* cw = dir ? cw1 : cw0;
  const float* cb = dir ? cb1 : cb0;
  const unsigned short* xpd = xpre + (size_t)dir*NTOK*DI;
  unsigned short* outp = xi_bf + (size_t)dir*NTOK*DI;

  float wv[4][8];
#pragma unroll
  for (int c=0;c<8;c++){
    float4 w = *reinterpret_cast<const float4*>(cw + (size_t)(d0+c)*4);
    wv[0][c]=w.x; wv[1][c]=w.y; wv[2][c]=w.z; wv[3][c]=w.w;
  }
  float bv[8];
  {
    float4 b0 = *reinterpret_cast<const float4*>(cb + d0);
    float4 b1 = *reinterpret_cast<const float4*>(cb + d0 + 4);
    bv[0]=b0.x; bv[1]=b0.y; bv[2]=b0.z; bv[3]=b0.w;
    bv[4]=b1.x; bv[5]=b1.y; bv[6]=b1.z; bv[7]=b1.w;
  }
  const int rbase = t0 + (dir ? 0 : -3);
  float rows[7][8];
#pragma unroll
  for (int i=0;i<7;i++){
    int r = rbase + i;
    if (r >= 0 && r < LL){
      union { i32x4 v; unsigned short u[8]; } x;
      x.v = *reinterpret_cast<const i32x4*>(xpd + ((size_t)b*LL + r)*DI + d0);
#pragma unroll
      for (int c=0;c<8;c++) rows[i][c] = bf2f(x.u[c]);
    } else {
#pragma unroll
      for (int c=0;c<8;c++) rows[i][c] = 0.f;
    }
  }
#pragma unroll
  for (int j=0;j<4;j++){
    union { i32x4 v; unsigned short u[8]; } o;
#pragma unroll
    for (int c=0;c<8;c++){
      float acc = bv[c];
#pragma unroll
      for (int m=0;m<4;m++){
        float w = dir ? wv[3-m][c] : wv[m][c];
        acc += w * rows[j+m][c];
      }
      o.u[c] = f2bf(siluf(acc));
    }
    *reinterpret_cast<i32x4*>(outp + ((size_t)(tok0+j))*DI + d0) = o.v;
  }
}

// reduce split-K partials -> xdbl f32 [2][NTOK][96]; bf16 of cols 0..63
__global__ __launch_bounds__(256) void k_xred(const float* __restrict__ part,
    float* __restrict__ xdbl, unsigned short* __restrict__ xdbl_bf){
  int idx = blockIdx.x*256 + threadIdx.x;
  if (idx >= 2*NTOK*96) return;
  int dir = idx / (NTOK*96);
  int rem = idx - dir*(NTOK*96);
  int tok = rem / 96, j = rem - tok*96;
  const float* pd = part + (size_t)dir*4*NTOK*128;
  const size_t czs = (size_t)NTOK*128;
  size_t o = (size_t)tok*128 + j;
  float v = pd[o] + pd[czs + o] + pd[2*czs + o] + pd[3*czs + o];
  xdbl[(size_t)dir*NTOK*96 + (size_t)tok*96 + j] = v;
  if (j < 64) xdbl_bf[(size_t)dir*NTOK*64 + (size_t)tok*64 + j] = f2bf(v);
}

// build dA[0..15] = q^(n+1) with a log-depth power tree (15 muls, depth 4)
__device__ __forceinline__ void powtree(float q, float* dA){
  dA[0]=q;
  dA[1]=dA[0]*dA[0];
  dA[2]=dA[1]*dA[0];
  dA[3]=dA[1]*dA[1];
  dA[4]=dA[3]*dA[0];
  dA[5]=dA[3]*dA[1];
  dA[6]=dA[3]*dA[2];
  dA[7]=dA[3]*dA[3];
#pragma unroll
  for (int n=8;n<16;n++) dA[n]=dA[7]*dA[n-8];
}
// check Alog2[n] ~= (n+1)*Alog2[0]  (S4D-real init); rel tol 1e-5
__device__ __forceinline__ bool chk_struct(const float* Alog2){
  bool ok = true;
  float a0 = Alog2[0];
#pragma unroll
  for (int n=1;n<16;n++){
    float e = a0*(float)(n+1);
    ok = ok && (fabsf(Alog2[n]-e) <= 1e-5f*fabsf(e) + 1e-12f);
  }
  return ok;
}

// ---- chunked selective scan (NC=64, CL=32), lane = channel, h[16] in regs ----
__global__ __launch_bounds__(256) void k_scan_p1(const unsigned short* __restrict__ u,
    const unsigned short* __restrict__ dt, const float* __restrict__ xdbl,
    const float* __restrict__ A_log0, const float* __restrict__ A_log1,
    float* __restrict__ hloc, float* __restrict__ dtsum){
  __shared__ float Bs[CL*16];
  const int dir = blockIdx.z;
  u    += (size_t)dir*NTOK*DI;
  dt   += (size_t)dir*NTOK*DI;
  xdbl += (size_t)dir*NTOK*96;
  const float* A_log = dir ? A_log1 : A_log0;
  const int tid = threadIdx.x;
  const int ch = blockIdx.x*256 + tid;
  const int c = blockIdx.y;
  const int b = (blockIdx.x*256) >> 11;
  const int d = ch & (DI-1);
  for (int i = tid; i < CL*16; i += 256){
    int s = i >> 4, j = i & 15;
    int sg = c*CL + s;
    int tt = dir ? (LL-1-sg) : sg;
    Bs[i] = xdbl[((size_t)b*LL + tt)*96 + 64 + j];
  }
  float Alog2[16];
  {
    const float4* ap = reinterpret_cast<const float4*>(A_log + (size_t)d*16);
#pragma unroll
    for (int q=0;q<4;q++){
      float4 v = ap[q];
      Alog2[q*4+0] = -__expf(v.x)*LOG2E;
      Alog2[q*4+1] = -__expf(v.y)*LOG2E;
      Alog2[q*4+2] = -__expf(v.z)*LOG2E;
      Alog2[q*4+3] = -__expf(v.w)*LOG2E;
    }
  }
  const bool structured = chk_struct(Alog2);
  __syncthreads();
  float h[16];
#pragma unroll
  for (int n=0;n<16;n++) h[n]=0.f;
  float dts = 0.f;
  int tok0 = b*LL + (dir ? (LL-1-c*CL) : c*CL);
  const unsigned short* up = u + (size_t)tok0*DI + d;
  const unsigned short* dtp = dt + (size_t)tok0*DI + d;
  const ptrdiff_t stp = dir ? -(ptrdiff_t)DI : (ptrdiff_t)DI;
  if (structured){
    const float a0 = Alog2[0];
#pragma unroll 2
    for (int s=0; s<CL; s++){
      float uv  = bf2f(*up); up += stp;
      float dtv = bf2f(*dtp); dtp += stp;
      float dtu = dtv*uv;
      dts += dtv;
      const f32x4* br = reinterpret_cast<const f32x4*>(&Bs[s*16]);
      f32x4 B0=br[0], B1=br[1], B2=br[2], B3=br[3];
      float dA[16];
      powtree(__builtin_amdgcn_exp2f(dtv*a0), dA);
#pragma unroll
      for (int n=0;n<16;n++){
        float Bv = (n<4)?B0[n&3] : (n<8)?B1[n&3] : (n<12)?B2[n&3] : B3[n&3];
        h[n] = dA[n]*h[n] + dtu*Bv;
      }
    }
  } else {
#pragma unroll 2
    for (int s=0; s<CL; s++){
      float uv  = bf2f(*up); up += stp;
      float dtv = bf2f(*dtp); dtp += stp;
      float dtu = dtv*uv;
      dts += dtv;
      const f32x4* br = reinterpret_cast<const f32x4*>(&Bs[s*16]);
      f32x4 B0=br[0], B1=br[1], B2=br[2], B3=br[3];
#pragma unroll
      for (int n=0;n<16;n++){
        float dA = __builtin_amdgcn_exp2f(dtv*Alog2[n]);
        float Bv = (n<4)?B0[n&3] : (n<8)?B1[n&3] : (n<12)?B2[n&3] : B3[n&3];
        h[n] = dA*h[n] + dtu*Bv;
      }
    }
  }
  float* hp = hloc + (((size_t)(dir*NC + c)*NCH + ch))*16;
#pragma unroll
  for (int q=0;q<4;q++)
    *reinterpret_cast<f32x4*>(hp + q*4) = f32x4{h[q*4],h[q*4+1],h[q*4+2],h[q*4+3]};
  dtsum[(size_t)(dir*NC + c)*NCH + ch] = dts;
}

// combine: per (dir,ch,n); pa = exp2(dtsum*Alog2[n]); hstart written over hloc
__global__ __launch_bounds__(256) void k_scan_comb(float* __restrict__ hloc,
    const float* __restrict__ dtsum,
    const float* __restrict__ A_log0, const float* __restrict__ A_log1){
  int i = blockIdx.x*256 + threadIdx.x;   // covers 2*NCH*16
  int dir = i / (NCH*16);
  int j = i - dir*(NCH*16);
  int ch = j >> 4, n = j & 15;
  int d = ch & (DI-1);
  const float* A_log = dir ? A_log1 : A_log0;
  float Alog2 = -__expf(A_log[(size_t)d*16 + n])*LOG2E;
  float hs = 0.f;
#pragma unroll 4
  for (int c=0; c<NC; c++){
    size_t base = (size_t)(dir*NC + c)*NCH + ch;
    float pa = __builtin_amdgcn_exp2f(dtsum[base]*Alog2);
    size_t idx = base*16 + n;
    float h = hloc[idx];
    hloc[idx] = hs;
    hs = pa*hs + h;
  }
}

// pass 2: rescan from hstart(=hloc); fused gate: g = bf16(y*silu(z)) over u
__global__ __launch_bounds__(256) void k_scan_p2(unsigned short* __restrict__ uy,
    const unsigned short* __restrict__ dt, const float* __restrict__ xdbl,
    const unsigned short* __restrict__ zbuf,
    const float* __restrict__ A_log0, const float* __restrict__ A_log1,
    const float* __restrict__ Dp0, const float* __restrict__ Dp1,
    const float* __restrict__ hstart){
  __shared__ float BCs[CL*32];
  const int dir = blockIdx.z;
  uy   += (size_t)dir*NTOK*DI;
  dt   += (size_t)dir*NTOK*DI;
  zbuf += (size_t)dir*NTOK*DI;
  xdbl += (size_t)dir*NTOK*96;
  const float* A_log = dir ? A_log1 : A_log0;
  const float* Dp = dir ? Dp1 : Dp0;
  const int tid = threadIdx.x;
  const int ch = blockIdx.x*256 + tid;
  const int c = blockIdx.y;
  const int b = (blockIdx.x*256) >> 11;
  const int d = ch & (DI-1);
  for (int i = tid; i < CL*32; i += 256){
    int s = i >> 5, j = i & 31;
    int sg = c*CL + s;
    int tt = dir ? (LL-1-sg) : sg;
    BCs[i] = xdbl[((size_t)b*LL + tt)*96 + 64 + j];
  }
  float Alog2[16];
  {
    const float4* ap = reinterpret_cast<const float4*>(A_log + (size_t)d*16);
#pragma unroll
    for (int q=0;q<4;q++){
      float4 v = ap[q];
      Alog2[q*4+0] = -__expf(v.x)*LOG2E;
      Alog2[q*4+1] = -__expf(v.y)*LOG2E;
      Alog2[q*4+2] = -__expf(v.z)*LOG2E;
      Alog2[q*4+3] = -__expf(v.w)*LOG2E;
    }
  }
  const bool structured = chk_struct(Alog2);
  float h[16];
  {
    const float* hp = hstart + (((size_t)(dir*NC + c)*NCH + ch))*16;
#pragma unroll
    for (int q=0;q<4;q++){
      f32x4 v = *reinterpret_cast<const f32x4*>(hp + q*4);
      h[q*4]=v[0]; h[q*4+1]=v[1]; h[q*4+2]=v[2]; h[q*4+3]=v[3];
    }
  }
  const float Dval = Dp[d];
  __syncthreads();
  int tok0 = b*LL + (dir ? (LL-1-c*CL) : c*CL);
  unsigned short* up = uy + (size_t)tok0*DI + d;
  const unsigned short* zp = zbuf + (size_t)tok0*DI + d;
  const unsigned short* dtp = dt + (size_t)tok0*DI + d;
  const ptrdiff_t stp = dir ? -(ptrdiff_t)DI : (ptrdiff_t)DI;
  if (structured){
    const float a0 = Alog2[0];
#pragma unroll 2
    for (int s=0; s<CL; s++){
      float uv  = bf2f(*up);
      float zv  = bf2f(*zp); zp += stp;
      float dtv = bf2f(*dtp); dtp += stp;
      float dtu = dtv*uv;
      float y = Dval*uv;
      const f32x4* br = reinterpret_cast<const f32x4*>(&BCs[s*32]);
      f32x4 B0=br[0], B1=br[1], B2=br[2], B3=br[3];
      f32x4 C0=br[4], C1=br[5], C2=br[6], C3=br[7];
      float dA[16];
      powtree(__builtin_amdgcn_exp2f(dtv*a0), dA);
#pragma unroll
      for (int n=0;n<16;n++){
        float Bv = (n<4)?B0[n&3] : (n<8)?B1[n&3] : (n<12)?B2[n&3] : B3[n&3];
        float Cv = (n<4)?C0[n&3] : (n<8)?C1[n&3] : (n<12)?C2[n&3] : C3[n&3];
        h[n] = dA[n]*h[n] + dtu*Bv;
        y += h[n]*Cv;
      }
      *up = f2bf(y * siluf(zv)); up += stp;
    }
  } else {
#pragma unroll 2
    for (int s=0; s<CL; s++){
      float uv  = bf2f(*up);
      float zv  = bf2f(*zp); zp += stp;
      float dtv = bf2f(*dtp); dtp += stp;
      float dtu = dtv*uv;
      float y = Dval*uv;
      const f32x4* br = reinterpret_cast<const f32x4*>(&BCs[s*32]);
      f32x4 B0=br[0], B1=br[1], B2=br[2], B3=br[3];
      f32x4 C0=br[4], C1=br[5], C2=br[6], C3=br[7];
#pragma unroll
      for (int n=0;n<16;n++){
        float dA = __builtin_amdgcn_exp2f(dtv*Alog2[n]);
        float Bv = (n<4)?B0[n&3] : (n<8)?B1[n&3] : (n<12)?B2[n&3] : B3[n&3];
        float Cv = (n<4)?C0[n&3] : (n<8)?C1[n&3] : (n<12)?C2[n&3] : C3[n&3];
        h[n] = dA*h[n] + dtu*Bv;
        y += h[n]*Cv;
      }
      *up = f2bf(y * siluf(zv)); up += stp;
    }
  }
}

extern "C" void kernel_launch(void* const* d_in, const int* in_sizes, int n_in,
                              void* d_out, int out_size, void* d_ws, size_t ws_size,
                              hipStream_t stream){
  (void)in_sizes; (void)n_in; (void)out_size; (void)ws_size;
  const float* x = (const float*)d_in[0];
  const float* ipw[2], *cw[2], *cb[2], *xpw[2], *dtw_[2], *dtb[2], *Alog[2], *Dp[2], *opw[2];
  for (int dir=0; dir<2; dir++){
    ipw[dir]  = (const float*)d_in[1 + dir*9 + 0];
    cw[dir]   = (const float*)d_in[1 + dir*9 + 1];
    cb[dir]   = (const float*)d_in[1 + dir*9 + 2];
    xpw[dir]  = (const float*)d_in[1 + dir*9 + 3];
    dtw_[dir] = (const float*)d_in[1 + dir*9 + 4];
    dtb[dir]  = (const float*)d_in[1 + dir*9 + 5];
    Alog[dir] = (const float*)d_in[1 + dir*9 + 6];
    Dp[dir]   = (const float*)d_in[1 + dir*9 + 7];
    opw[dir]  = (const float*)d_in[1 + dir*9 + 8];
  }
  char* p = (char*)d_ws;
  auto alloc = [&](size_t bytes)->void*{ void* r=(void*)p; p += (bytes+255)&~(size_t)255; return r; };
  // sequential allocations (~166 MiB total)
  unsigned short* x_bf   = (unsigned short*)alloc((size_t)NTOK*DM*2);        // [0,8) MiB
  unsigned short* w_bf   = (unsigned short*)alloc((size_t)2*(2*DI)*DM*2);    // [8,24) MiB
  float* part            = (float*)w_bf;                                      // alias
  unsigned short* xpre   = (unsigned short*)alloc((size_t)2*NTOK*DI*2);      // [24,56) MiB
  unsigned short* zbuf   = (unsigned short*)alloc((size_t)2*NTOK*DI*2);      // 32 MiB
  unsigned short* xi_bf  = (unsigned short*)alloc((size_t)2*NTOK*DI*2);      // 32 MiB (u, then g)
  float* xdbl            = (float*)alloc((size_t)2*NTOK*96*4);               // 3 MiB
  unsigned short* xdbl_bf= (unsigned short*)alloc((size_t)2*NTOK*64*2);      // 1 MiB
  unsigned short* dt_bf  = (unsigned short*)alloc((size_t)2*NTOK*DI*2);      // 32 MiB
  unsigned short* wpad   = (unsigned short*)alloc((size_t)2*128*DI*2);       // 1 MiB
  unsigned short* dtw_bf = (unsigned short*)alloc((size_t)2*DI*64*2);        // 0.5 MiB
  unsigned short* outw   = (unsigned short*)alloc((size_t)2*DM*DI*2);        // 8 MiB
  // scan temporaries overlay the dead-by-scan-time region [0,56) MiB
  float* hloc  = (float*)d_ws;                                    // [0,32) MiB
  float* dtsum = (float*)((char*)d_ws + (size_t)32*1024*1024);    // [32,34) MiB

  // all casts in one dispatch
  k_cast_all<<<CAST_BLOCKS, 256, 0, stream>>>(
      x, ipw[0], ipw[1], xpw[0], xpw[1], dtw_[0], dtw_[1], opw[0], opw[1],
      x_bf, w_bf, wpad, dtw_bf, outw);

  // in_proj: 256^2 ring-pipelined GEMM; cols [0,2048)->xpre, [2048,4096)->zbuf
  k_gemm256<16,256,unsigned short><<<dim3(16,16,2), 512, 0, stream>>>(
      x_bf, DM, 0, w_bf, DM, (long long)(2*DI)*DM,
      xpre, zbuf, DI, DI, (long long)NTOK*DI);
  // conv + silu -> u (bf16), vectorized 8ch x 4tok per thread
  k_conv_silu<<<dim3(NTOK/4,1,2), 256, 0, stream>>>(xpre, cw[0], cw[1], cb[0], cb[1], xi_bf);
  // xproj (split-K=4, both dirs): part[z] = u_z @ wpad_z^T   (part aliases w_bf)
  k_gemm_bt<0,4,float><<<dim3(1,32,8), 256, 0, stream>>>(
      xi_bf, DI, (long long)NTOK*DI, wpad, DI, (long long)128*DI,
      part, part, 1<<30, 128, (long long)NTOK*128, 0, 512, 0, nullptr, nullptr);
  k_xred<<<(2*NTOK*96+255)/256, 256, 0, stream>>>(part, xdbl, xdbl_bf);
  // dt = softplus(xdbl[:, :64] @ dtw^T + b), stored bf16
  k_gemm_bt<1,1,unsigned short><<<dim3(16,32,2), 256, 0, stream>>>(
      xdbl_bf, 64, (long long)NTOK*64, dtw_bf, 64, (long long)DI*64,
      dt_bf, dt_bf, 1<<30, DI, (long long)NTOK*DI, 0, 64, 0, dtb[0], dtb[1]);
  // chunked scan (NC=64): hloc/dtsum overlay dead region
  k_scan_p1<<<dim3(NCH/256, NC, 2), 256, 0, stream>>>(xi_bf, dt_bf, xdbl,
      Alog[0], Alog[1], hloc, dtsum);
  k_scan_comb<<<2*NCH*16/256, 256, 0, stream>>>(hloc, dtsum, Alog[0], Alog[1]);
  k_scan_p2<<<dim3(NCH/256, NC, 2), 256, 0, stream>>>(xi_bf, dt_bf, xdbl, zbuf,
      Alog[0], Alog[1], Dp[0], Dp[1], hloc);
  // out = g @ out_proj^T on the ring-pipelined 256x128 kernel; dir offsets cols by DM
  k_gemm256<32,128,float><<<dim3(8,16,2), 512, 0, stream>>>(
      xi_bf, DI, (long long)NTOK*DI, outw, DI, (long long)DM*DI,
      (float*)d_out, (float*)d_out, 1<<30, 2*DM, (long long)DM);
}